// Round 1
// baseline (453.547 us; speedup 1.0000x reference)
//
#include <hip/hip_runtime.h>
#include <math.h>

#define N_NODES 50000
#define N_EDGES 800000
#define F_IN    512
#define H1      8
#define F_HID   8
#define C1      64      // H1*F_HID
#define NLAB    64
#define SLOPE   0.2f

#define NBLK_SCAN 196   // ceil(50000/256)

// ---------------- W1 transpose: [H,F,O] -> [F, H*O] ----------------
__global__ void k_wt(const float* __restrict__ W1, float* __restrict__ Wt) {
    int i = blockIdx.x * 256 + threadIdx.x;
    if (i >= F_IN * C1) return;
    int f = i >> 6, c = i & 63;
    Wt[i] = W1[(c >> 3) * (F_IN * F_HID) + f * F_HID + (c & 7)];
}

// ---------------- GEMM1: X[50000,512] @ Wt[512,64] -> Wh1[50000,64] ----------------
__launch_bounds__(256)
__global__ void k_gemm1(const float* __restrict__ X, const float* __restrict__ Wt,
                        float* __restrict__ Wh) {
    __shared__ float As[64 * 68];   // [row][k], pad 68
    __shared__ float Bs[64 * 64];   // [k][c]
    const int t = threadIdx.x;
    const int row0 = blockIdx.x * 64;
    const int c4 = (t & 15) * 4;
    const int r4 = (t >> 4) * 4;
    float acc[4][4] = {};

    for (int kt = 0; kt < F_IN; kt += 64) {
        // stage A: 64 rows x 64 k
        #pragma unroll
        for (int i = 0; i < 4; i++) {
            int flat = i * 256 + t;        // 0..1023 float4 slots
            int r = flat >> 4;             // 0..63
            int kq = flat & 15;            // 0..15
            int gr = row0 + r; if (gr >= N_NODES) gr = N_NODES - 1;
            float4 v = *(const float4*)(X + (size_t)gr * F_IN + kt + kq * 4);
            *(float4*)(As + r * 68 + kq * 4) = v;
        }
        // stage B: 64 k x 64 c
        #pragma unroll
        for (int i = 0; i < 4; i++) {
            int flat = i * 256 + t;
            int k = flat >> 4;
            int cq = flat & 15;
            float4 v = *(const float4*)(Wt + (kt + k) * 64 + cq * 4);
            *(float4*)(Bs + k * 64 + cq * 4) = v;
        }
        __syncthreads();
        #pragma unroll
        for (int k4 = 0; k4 < 16; k4++) {
            float4 A0 = *(const float4*)(As + (r4 + 0) * 68 + k4 * 4);
            float4 A1 = *(const float4*)(As + (r4 + 1) * 68 + k4 * 4);
            float4 A2 = *(const float4*)(As + (r4 + 2) * 68 + k4 * 4);
            float4 A3 = *(const float4*)(As + (r4 + 3) * 68 + k4 * 4);
            float4 B0 = *(const float4*)(Bs + (k4 * 4 + 0) * 64 + c4);
            float4 B1 = *(const float4*)(Bs + (k4 * 4 + 1) * 64 + c4);
            float4 B2 = *(const float4*)(Bs + (k4 * 4 + 2) * 64 + c4);
            float4 B3 = *(const float4*)(Bs + (k4 * 4 + 3) * 64 + c4);
            float av[4][4] = {{A0.x,A0.y,A0.z,A0.w},{A1.x,A1.y,A1.z,A1.w},
                              {A2.x,A2.y,A2.z,A2.w},{A3.x,A3.y,A3.z,A3.w}};
            float bv[4][4] = {{B0.x,B0.y,B0.z,B0.w},{B1.x,B1.y,B1.z,B1.w},
                              {B2.x,B2.y,B2.z,B2.w},{B3.x,B3.y,B3.z,B3.w}};
            #pragma unroll
            for (int j = 0; j < 4; j++)
                #pragma unroll
                for (int kk = 0; kk < 4; kk++)
                    #pragma unroll
                    for (int i = 0; i < 4; i++)
                        acc[j][i] += av[j][kk] * bv[kk][i];
        }
        __syncthreads();
    }
    #pragma unroll
    for (int j = 0; j < 4; j++) {
        int gr = row0 + r4 + j;
        if (gr < N_NODES) {
            float4 v = make_float4(acc[j][0], acc[j][1], acc[j][2], acc[j][3]);
            *(float4*)(Wh + (size_t)gr * 64 + c4) = v;
        }
    }
}

// ---------------- es/ed for layer 1 ----------------
__global__ void k_esed1(const float* __restrict__ Wh, const float* __restrict__ a_s,
                        const float* __restrict__ a_d, float* __restrict__ es,
                        float* __restrict__ ed) {
    int i = blockIdx.x * 256 + threadIdx.x;
    if (i >= N_NODES * H1) return;
    int n = i >> 3, h = i & 7;
    const float* w = Wh + (size_t)n * 64 + h * 8;
    float s = 0.f, d = 0.f;
    #pragma unroll
    for (int j = 0; j < 8; j++) {
        float v = w[j];
        s += v * a_s[h * 8 + j];
        d += v * a_d[h * 8 + j];
    }
    es[i] = s;
    ed[i] = d;
}

// ---------------- CSR build ----------------
__global__ void k_hist(const int* __restrict__ dst, int* __restrict__ deg) {
    int e = blockIdx.x * 256 + threadIdx.x;
    if (e < N_EDGES) atomicAdd(&deg[dst[e]], 1);
}

__global__ void k_scan1(const int* __restrict__ deg, int* __restrict__ rowptr,
                        int* __restrict__ bsums) {
    __shared__ int s[256];
    int t = threadIdx.x;
    int g = blockIdx.x * 256 + t;
    int v = (g < N_NODES) ? deg[g] : 0;
    s[t] = v;
    __syncthreads();
    #pragma unroll
    for (int off = 1; off < 256; off <<= 1) {
        int a = s[t];
        int b = (t >= off) ? s[t - off] : 0;
        __syncthreads();
        s[t] = a + b;
        __syncthreads();
    }
    if (g < N_NODES) rowptr[g] = s[t] - v;   // exclusive (block-local)
    if (t == 255) bsums[blockIdx.x] = s[t];
}

__global__ void k_scan2(const int* __restrict__ bsums, int* __restrict__ boffs) {
    __shared__ int s[256];
    int t = threadIdx.x;
    int v = (t < NBLK_SCAN) ? bsums[t] : 0;
    s[t] = v;
    __syncthreads();
    #pragma unroll
    for (int off = 1; off < 256; off <<= 1) {
        int a = s[t];
        int b = (t >= off) ? s[t - off] : 0;
        __syncthreads();
        s[t] = a + b;
        __syncthreads();
    }
    if (t < NBLK_SCAN) boffs[t] = s[t] - v;  // exclusive
}

__global__ void k_scan3(int* __restrict__ rowptr, const int* __restrict__ boffs) {
    int g = blockIdx.x * 256 + threadIdx.x;
    if (g < N_NODES) rowptr[g] += boffs[blockIdx.x];
}

__global__ void k_scatter(const int* __restrict__ src, const int* __restrict__ dst,
                          const int* __restrict__ rowptr, int* __restrict__ fill,
                          int* __restrict__ col) {
    int e = blockIdx.x * 256 + threadIdx.x;
    if (e >= N_EDGES) return;
    int d = dst[e];
    int pos = rowptr[d] + atomicAdd(&fill[d], 1);
    col[pos] = src[e];
}

// ---------------- layer-1 attention aggregation (one wave per node) ----------------
__launch_bounds__(256)
__global__ void k_agg1(const float* __restrict__ Wh, const float* __restrict__ es,
                       const float* __restrict__ ed, const int* __restrict__ rowptr,
                       const int* __restrict__ deg, const int* __restrict__ col,
                       float* __restrict__ h2) {
    int wv = threadIdx.x >> 6;
    int lane = threadIdx.x & 63;
    int n = blockIdx.x * 4 + wv;
    if (n >= N_NODES) return;
    int start = rowptr[n];
    int d = deg[n];

    // loop 1: per-head running max. lane = eo*8 + h
    int h = lane & 7;
    int eo = lane >> 3;
    float edh = ed[n * 8 + h];
    float m = -1e30f;
    for (int base = 0; base < d; base += 8) {
        float s = -1e30f;
        int idx = base + eo;
        if (idx < d) {
            int sv = col[start + idx];
            float x = es[sv * 8 + h] + edh;
            s = x > 0.f ? x : SLOPE * x;
        }
        s = fmaxf(s, __shfl_xor(s, 8));
        s = fmaxf(s, __shfl_xor(s, 16));
        s = fmaxf(s, __shfl_xor(s, 32));
        m = fmaxf(m, s);
    }
    // remap: lane c owns output col c, head hc = c>>3; lane hc holds max for head hc
    int hc = lane >> 3;
    float mh = __shfl(m, hc);
    float edh2 = ed[n * 8 + hc];
    float den = 0.f, acc = 0.f;
    for (int base = 0; base < d; base += 64) {
        int sv64 = 0;
        if (base + lane < d) sv64 = col[start + base + lane];
        int cnt = min(64, d - base);
        for (int j = 0; j < cnt; j++) {
            int sv = __shfl(sv64, j);
            float x = es[sv * 8 + hc] + edh2;
            x = x > 0.f ? x : SLOPE * x;
            float wgt = __expf(x - mh);
            den += wgt;
            acc += wgt * Wh[(size_t)sv * 64 + lane];
        }
    }
    float o = acc / (den + 1e-10f);
    // fused ELU (concat-heads layout already matches [n, h*8+o])
    h2[(size_t)n * 64 + lane] = o > 0.f ? o : expm1f(o);
}

// ---------------- GEMM2 (K=64) + fused es2/ed2 epilogue ----------------
__launch_bounds__(256)
__global__ void k_gemm2(const float* __restrict__ h2, const float* __restrict__ W2,
                        const float* __restrict__ a2s, const float* __restrict__ a2d,
                        float* __restrict__ Wh2, float* __restrict__ es2,
                        float* __restrict__ ed2) {
    __shared__ float Ws[64 * 64];
    __shared__ float hs[4][64];
    int t = threadIdx.x;
    #pragma unroll
    for (int i = 0; i < 4; i++) {
        int flat = i * 256 + t;   // 1024 float4 slots
        *(float4*)(Ws + flat * 4) = *(const float4*)(W2 + flat * 4);
    }
    int wv = t >> 6, lane = t & 63;
    int n = blockIdx.x * 4 + wv;
    bool valid = n < N_NODES;
    float hv = valid ? h2[(size_t)n * 64 + lane] : 0.f;
    hs[wv][lane] = hv;
    __syncthreads();
    if (!valid) return;   // wave-uniform; no further barriers
    float acc = 0.f;
    #pragma unroll
    for (int k = 0; k < 64; k++) acc += hs[wv][k] * Ws[k * 64 + lane];
    Wh2[(size_t)n * 64 + lane] = acc;
    float s = acc * a2s[lane];
    float dd = acc * a2d[lane];
    #pragma unroll
    for (int off = 1; off < 64; off <<= 1) {
        s += __shfl_xor(s, off);
        dd += __shfl_xor(dd, off);
    }
    if (lane == 0) { es2[n] = s; ed2[n] = dd; }
}

// ---------------- layer-2 aggregation + fused final softmax ----------------
__launch_bounds__(256)
__global__ void k_agg2(const float* __restrict__ Wh2, const float* __restrict__ es2,
                       const float* __restrict__ ed2, const int* __restrict__ rowptr,
                       const int* __restrict__ deg, const int* __restrict__ col,
                       float* __restrict__ out) {
    int wv = threadIdx.x >> 6, lane = threadIdx.x & 63;
    int n = blockIdx.x * 4 + wv;
    if (n >= N_NODES) return;
    int start = rowptr[n], d = deg[n];
    float edn = ed2[n];
    float m = -1e30f;
    for (int base = 0; base < d; base += 64) {
        float s = -1e30f;
        if (base + lane < d) {
            int sv = col[start + base + lane];
            float x = es2[sv] + edn;
            s = x > 0.f ? x : SLOPE * x;
        }
        m = fmaxf(m, s);
    }
    #pragma unroll
    for (int off = 1; off < 64; off <<= 1) m = fmaxf(m, __shfl_xor(m, off));
    float den = 0.f, acc = 0.f;
    for (int base = 0; base < d; base += 64) {
        int sv64 = (base + lane < d) ? col[start + base + lane] : 0;
        int cnt = min(64, d - base);
        for (int j = 0; j < cnt; j++) {
            int sv = __shfl(sv64, j);
            float x = es2[sv] + edn;
            x = x > 0.f ? x : SLOPE * x;
            float wgt = __expf(x - m);
            den += wgt;
            acc += wgt * Wh2[(size_t)sv * 64 + lane];
        }
    }
    float o = acc / (den + 1e-10f);
    // fused softmax over the 64 classes (one wave = one row)
    float mx = o;
    #pragma unroll
    for (int off = 1; off < 64; off <<= 1) mx = fmaxf(mx, __shfl_xor(mx, off));
    float e = __expf(o - mx);
    float sm = e;
    #pragma unroll
    for (int off = 1; off < 64; off <<= 1) sm += __shfl_xor(sm, off);
    out[(size_t)n * 64 + lane] = e / sm;
}

// ---------------- launcher ----------------
extern "C" void kernel_launch(void* const* d_in, const int* in_sizes, int n_in,
                              void* d_out, int out_size, void* d_ws, size_t ws_size,
                              hipStream_t stream) {
    const float* X   = (const float*)d_in[0];
    const float* W1  = (const float*)d_in[1];
    const float* a1s = (const float*)d_in[2];
    const float* a1d = (const float*)d_in[3];
    const float* W2  = (const float*)d_in[4];
    const float* a2s = (const float*)d_in[5];
    const float* a2d = (const float*)d_in[6];
    const int*   src = (const int*)d_in[7];
    const int*   dst = (const int*)d_in[8];
    float* out = (float*)d_out;

    char* w = (char*)d_ws;
    size_t off = 0;
    auto alloc = [&](size_t bytes) {
        void* p = w + off;
        off += (bytes + 255) & ~(size_t)255;
        return p;
    };
    float* Wt    = (float*)alloc((size_t)F_IN * 64 * 4);
    float* WH    = (float*)alloc((size_t)N_NODES * 64 * 4);  // Wh1, later reused as Wh2
    float* h2    = (float*)alloc((size_t)N_NODES * 64 * 4);
    float* es1   = (float*)alloc((size_t)N_NODES * 8 * 4);
    float* ed1   = (float*)alloc((size_t)N_NODES * 8 * 4);
    float* es2   = (float*)alloc((size_t)N_NODES * 4);
    float* ed2   = (float*)alloc((size_t)N_NODES * 4);
    int*   deg   = (int*)alloc((size_t)N_NODES * 4);
    int*   fill  = (int*)alloc((size_t)N_NODES * 4);
    int*   rowptr= (int*)alloc((size_t)N_NODES * 4);
    int*   col   = (int*)alloc((size_t)N_EDGES * 4);
    int*   bsums = (int*)alloc(256 * 4);
    int*   boffs = (int*)alloc(256 * 4);

    hipMemsetAsync(deg, 0, (size_t)N_NODES * 4, stream);
    hipMemsetAsync(fill, 0, (size_t)N_NODES * 4, stream);

    // CSR build
    k_hist<<<(N_EDGES + 255) / 256, 256, 0, stream>>>(dst, deg);
    k_scan1<<<NBLK_SCAN, 256, 0, stream>>>(deg, rowptr, bsums);
    k_scan2<<<1, 256, 0, stream>>>(bsums, boffs);
    k_scan3<<<NBLK_SCAN, 256, 0, stream>>>(rowptr, boffs);
    k_scatter<<<(N_EDGES + 255) / 256, 256, 0, stream>>>(src, dst, rowptr, fill, col);

    // layer 1
    k_wt<<<(F_IN * C1 + 255) / 256, 256, 0, stream>>>(W1, Wt);
    k_gemm1<<<(N_NODES + 63) / 64, 256, 0, stream>>>(X, Wt, WH);
    k_esed1<<<(N_NODES * H1 + 255) / 256, 256, 0, stream>>>(WH, a1s, a1d, es1, ed1);
    k_agg1<<<(N_NODES + 3) / 4, 256, 0, stream>>>(WH, es1, ed1, rowptr, deg, col, h2);

    // layer 2 (WH reused as Wh2)
    k_gemm2<<<(N_NODES + 3) / 4, 256, 0, stream>>>(h2, W2, a2s, a2d, WH, es2, ed2);
    k_agg2<<<(N_NODES + 3) / 4, 256, 0, stream>>>(WH, es2, ed2, rowptr, deg, col, out);
}

// Round 2
// 406.734 us; speedup vs baseline: 1.1151x; 1.1151x over previous
//
#include <hip/hip_runtime.h>
#include <math.h>

#define N_NODES 50000
#define N_EDGES 800000
#define F_IN    512
#define H1      8
#define F_HID   8
#define C1      64      // H1*F_HID
#define NLAB    64
#define SLOPE   0.2f

#define NBLK_SCAN 196   // ceil(50000/256)

typedef __attribute__((ext_vector_type(8))) short short8;
typedef __attribute__((ext_vector_type(4))) float f32x4;

// ---------------- W1 -> B^T bf16 hi/lo: Bh/Bl[c][f], c=0..63, f=0..511 ----------------
__global__ void k_wt(const float* __restrict__ W1, unsigned short* __restrict__ Bh,
                     unsigned short* __restrict__ Bl) {
    int i = blockIdx.x * 256 + threadIdx.x;
    if (i >= C1 * F_IN) return;
    int c = i >> 9, f = i & 511;
    float v = W1[(c >> 3) * (F_IN * F_HID) + f * F_HID + (c & 7)];
    unsigned bits = __float_as_uint(v);
    unsigned hb = bits & 0xFFFF0000u;
    float r = v - __uint_as_float(hb);
    Bh[i] = (unsigned short)(bits >> 16);
    Bl[i] = (unsigned short)(__float_as_uint(r) >> 16);
}

// ---------------- GEMM1 via bf16-split MFMA: X[50000,512] @ Wt[512,64] -> Wh[50000,64] ----------------
// One wave per 16 rows. No LDS, no barriers. A from global fp32 (split in regs),
// B^T hi/lo from L2-resident 128KB table.
__launch_bounds__(64)
__global__ void k_gemm1(const float* __restrict__ X, const unsigned short* __restrict__ Bh,
                        const unsigned short* __restrict__ Bl, float* __restrict__ Wh) {
    const int lane = threadIdx.x;
    const int r0 = blockIdx.x * 16;
    const int m = lane & 15;          // A row / C col index
    const int quad = lane >> 4;       // k-octet selector
    const float* xrow = X + (size_t)(r0 + m) * F_IN + quad * 8;

    f32x4 acc[4] = {};                // 4 n-subtiles of 16 cols

    #pragma unroll 2
    for (int kt = 0; kt < F_IN; kt += 32) {
        float4 xa = *(const float4*)(xrow + kt);
        float4 xb = *(const float4*)(xrow + kt + 4);
        float xs[8] = {xa.x, xa.y, xa.z, xa.w, xb.x, xb.y, xb.z, xb.w};
        short8 ah, al;
        #pragma unroll
        for (int j = 0; j < 8; j++) {
            unsigned bits = __float_as_uint(xs[j]);
            float r = xs[j] - __uint_as_float(bits & 0xFFFF0000u);
            ah[j] = (short)(bits >> 16);
            al[j] = (short)(__float_as_uint(r) >> 16);
        }
        #pragma unroll
        for (int s = 0; s < 4; s++) {
            const size_t boff = (size_t)(s * 16 + m) * F_IN + kt + quad * 8;
            short8 bh = *(const short8*)(Bh + boff);
            short8 bl = *(const short8*)(Bl + boff);
            acc[s] = __builtin_amdgcn_mfma_f32_16x16x32_bf16(al, bh, acc[s], 0, 0, 0);
            acc[s] = __builtin_amdgcn_mfma_f32_16x16x32_bf16(ah, bl, acc[s], 0, 0, 0);
            acc[s] = __builtin_amdgcn_mfma_f32_16x16x32_bf16(ah, bh, acc[s], 0, 0, 0);
        }
    }
    // C/D: col = lane&15 (within subtile), row = quad*4 + reg
    #pragma unroll
    for (int s = 0; s < 4; s++)
        #pragma unroll
        for (int reg = 0; reg < 4; reg++)
            Wh[(size_t)(r0 + quad * 4 + reg) * 64 + s * 16 + m] = acc[s][reg];
}

// ---------------- es/ed for layer 1 ----------------
__global__ void k_esed1(const float* __restrict__ Wh, const float* __restrict__ a_s,
                        const float* __restrict__ a_d, float* __restrict__ es,
                        float* __restrict__ ed) {
    int i = blockIdx.x * 256 + threadIdx.x;
    if (i >= N_NODES * H1) return;
    int n = i >> 3, h = i & 7;
    const float* w = Wh + (size_t)n * 64 + h * 8;
    float s = 0.f, d = 0.f;
    #pragma unroll
    for (int j = 0; j < 8; j++) {
        float v = w[j];
        s += v * a_s[h * 8 + j];
        d += v * a_d[h * 8 + j];
    }
    es[i] = s;
    ed[i] = d;
}

// ---------------- CSR build ----------------
__global__ void k_hist(const int* __restrict__ dst, int* __restrict__ deg) {
    int e = blockIdx.x * 256 + threadIdx.x;
    if (e < N_EDGES) atomicAdd(&deg[dst[e]], 1);
}

__global__ void k_scan1(const int* __restrict__ deg, int* __restrict__ rowptr,
                        int* __restrict__ bsums) {
    __shared__ int s[256];
    int t = threadIdx.x;
    int g = blockIdx.x * 256 + t;
    int v = (g < N_NODES) ? deg[g] : 0;
    s[t] = v;
    __syncthreads();
    #pragma unroll
    for (int off = 1; off < 256; off <<= 1) {
        int a = s[t];
        int b = (t >= off) ? s[t - off] : 0;
        __syncthreads();
        s[t] = a + b;
        __syncthreads();
    }
    if (g < N_NODES) rowptr[g] = s[t] - v;
    if (t == 255) bsums[blockIdx.x] = s[t];
}

__global__ void k_scan2(const int* __restrict__ bsums, int* __restrict__ boffs) {
    __shared__ int s[256];
    int t = threadIdx.x;
    int v = (t < NBLK_SCAN) ? bsums[t] : 0;
    s[t] = v;
    __syncthreads();
    #pragma unroll
    for (int off = 1; off < 256; off <<= 1) {
        int a = s[t];
        int b = (t >= off) ? s[t - off] : 0;
        __syncthreads();
        s[t] = a + b;
        __syncthreads();
    }
    if (t < NBLK_SCAN) boffs[t] = s[t] - v;
}

__global__ void k_scan3(int* __restrict__ rowptr, const int* __restrict__ boffs) {
    int g = blockIdx.x * 256 + threadIdx.x;
    if (g < N_NODES) rowptr[g] += boffs[blockIdx.x];
}

__global__ void k_scatter(const int* __restrict__ src, const int* __restrict__ dst,
                          const int* __restrict__ rowptr, int* __restrict__ fill,
                          int* __restrict__ col) {
    int e = blockIdx.x * 256 + threadIdx.x;
    if (e >= N_EDGES) return;
    int d = dst[e];
    int pos = rowptr[d] + atomicAdd(&fill[d], 1);
    col[pos] = src[e];
}

// ---------------- layer-1 attention aggregation ----------------
// wave per node; lane = g*8+q: group g handles edges e===g (mod 8), lane holds
// head q / channels 8q..8q+7. 8 edges per dependent-latency round.
__launch_bounds__(256)
__global__ void k_agg1(const float* __restrict__ Wh, const float* __restrict__ es,
                       const float* __restrict__ ed, const int* __restrict__ rowptr,
                       const int* __restrict__ deg, const int* __restrict__ col,
                       float* __restrict__ h2) {
    int wv = threadIdx.x >> 6, lane = threadIdx.x & 63;
    int n = blockIdx.x * 4 + wv;
    if (n >= N_NODES) return;
    int start = rowptr[n], d = deg[n];
    int g = lane >> 3, q = lane & 7;
    float edq = ed[n * 8 + q];

    float m = -1e30f;
    for (int base = 0; base < d; base += 8) {
        int e = base + g;
        if (e < d) {
            int sv = col[start + e];
            float x = es[sv * 8 + q] + edq;
            x = x > 0.f ? x : SLOPE * x;
            m = fmaxf(m, x);
        }
    }
    m = fmaxf(m, __shfl_xor(m, 8));
    m = fmaxf(m, __shfl_xor(m, 16));
    m = fmaxf(m, __shfl_xor(m, 32));   // all lanes: per-head-q max

    float den = 0.f;
    float acc[8] = {};
    for (int base = 0; base < d; base += 8) {
        int e = base + g;
        if (e < d) {
            int sv = col[start + e];
            float x = es[sv * 8 + q] + edq;
            x = x > 0.f ? x : SLOPE * x;
            float w = __expf(x - m);
            den += w;
            const float* wp = Wh + (size_t)sv * 64 + q * 8;
            float4 v0 = *(const float4*)(wp);
            float4 v1 = *(const float4*)(wp + 4);
            acc[0] += w * v0.x; acc[1] += w * v0.y; acc[2] += w * v0.z; acc[3] += w * v0.w;
            acc[4] += w * v1.x; acc[5] += w * v1.y; acc[6] += w * v1.z; acc[7] += w * v1.w;
        }
    }
    #pragma unroll
    for (int off = 8; off <= 32; off <<= 1) {
        den += __shfl_xor(den, off);
        #pragma unroll
        for (int j = 0; j < 8; j++) acc[j] += __shfl_xor(acc[j], off);
    }
    if (g == 0) {
        float inv = 1.f / (den + 1e-10f);
        float o[8];
        #pragma unroll
        for (int j = 0; j < 8; j++) {
            float v = acc[j] * inv;
            o[j] = v > 0.f ? v : expm1f(v);   // fused ELU
        }
        float4* hp = (float4*)(h2 + (size_t)n * 64 + q * 8);
        hp[0] = make_float4(o[0], o[1], o[2], o[3]);
        hp[1] = make_float4(o[4], o[5], o[6], o[7]);
    }
}

// ---------------- GEMM2 (K=64) + fused es2/ed2 epilogue ----------------
__launch_bounds__(256)
__global__ void k_gemm2(const float* __restrict__ h2, const float* __restrict__ W2,
                        const float* __restrict__ a2s, const float* __restrict__ a2d,
                        float* __restrict__ Wh2, float* __restrict__ es2,
                        float* __restrict__ ed2) {
    __shared__ float Ws[64 * 64];
    __shared__ float hs[4][64];
    int t = threadIdx.x;
    #pragma unroll
    for (int i = 0; i < 4; i++) {
        int flat = i * 256 + t;
        *(float4*)(Ws + flat * 4) = *(const float4*)(W2 + flat * 4);
    }
    int wv = t >> 6, lane = t & 63;
    int n = blockIdx.x * 4 + wv;
    bool valid = n < N_NODES;
    float hv = valid ? h2[(size_t)n * 64 + lane] : 0.f;
    hs[wv][lane] = hv;
    __syncthreads();
    if (!valid) return;
    float acc = 0.f;
    #pragma unroll
    for (int k = 0; k < 64; k++) acc += hs[wv][k] * Ws[k * 64 + lane];
    Wh2[(size_t)n * 64 + lane] = acc;
    float s = acc * a2s[lane];
    float dd = acc * a2d[lane];
    #pragma unroll
    for (int off = 1; off < 64; off <<= 1) {
        s += __shfl_xor(s, off);
        dd += __shfl_xor(dd, off);
    }
    if (lane == 0) { es2[n] = s; ed2[n] = dd; }
}

// ---------------- layer-2 aggregation + fused final softmax ----------------
__launch_bounds__(256)
__global__ void k_agg2(const float* __restrict__ Wh2, const float* __restrict__ es2,
                       const float* __restrict__ ed2, const int* __restrict__ rowptr,
                       const int* __restrict__ deg, const int* __restrict__ col,
                       float* __restrict__ out) {
    int wv = threadIdx.x >> 6, lane = threadIdx.x & 63;
    int n = blockIdx.x * 4 + wv;
    if (n >= N_NODES) return;
    int start = rowptr[n], d = deg[n];
    int g = lane >> 3, q = lane & 7;
    float edn = ed2[n];

    float m = -1e30f;
    for (int base = 0; base < d; base += 8) {
        int e = base + g;
        if (e < d) {
            int sv = col[start + e];
            float x = es2[sv] + edn;
            x = x > 0.f ? x : SLOPE * x;
            m = fmaxf(m, x);
        }
    }
    m = fmaxf(m, __shfl_xor(m, 8));
    m = fmaxf(m, __shfl_xor(m, 16));
    m = fmaxf(m, __shfl_xor(m, 32));

    float den = 0.f;
    float acc[8] = {};
    for (int base = 0; base < d; base += 8) {
        int e = base + g;
        if (e < d) {
            int sv = col[start + e];
            float x = es2[sv] + edn;
            x = x > 0.f ? x : SLOPE * x;
            float w = __expf(x - m);
            den += w;
            const float* wp = Wh2 + (size_t)sv * 64 + q * 8;
            float4 v0 = *(const float4*)(wp);
            float4 v1 = *(const float4*)(wp + 4);
            acc[0] += w * v0.x; acc[1] += w * v0.y; acc[2] += w * v0.z; acc[3] += w * v0.w;
            acc[4] += w * v1.x; acc[5] += w * v1.y; acc[6] += w * v1.z; acc[7] += w * v1.w;
        }
    }
    #pragma unroll
    for (int off = 8; off <= 32; off <<= 1) {
        den += __shfl_xor(den, off);
        #pragma unroll
        for (int j = 0; j < 8; j++) acc[j] += __shfl_xor(acc[j], off);
    }
    float inv = 1.f / (den + 1e-10f);
    float o[8];
    #pragma unroll
    for (int j = 0; j < 8; j++) o[j] = acc[j] * inv;
    // fused softmax over 64 classes: lane q holds channels 8q..8q+7 (all g duplicate)
    float mx = o[0];
    #pragma unroll
    for (int j = 1; j < 8; j++) mx = fmaxf(mx, o[j]);
    mx = fmaxf(mx, __shfl_xor(mx, 1));
    mx = fmaxf(mx, __shfl_xor(mx, 2));
    mx = fmaxf(mx, __shfl_xor(mx, 4));
    float e8[8], sm = 0.f;
    #pragma unroll
    for (int j = 0; j < 8; j++) { e8[j] = __expf(o[j] - mx); sm += e8[j]; }
    sm += __shfl_xor(sm, 1);
    sm += __shfl_xor(sm, 2);
    sm += __shfl_xor(sm, 4);
    if (g == 0) {
        float inv2 = 1.f / sm;
        float4* op = (float4*)(out + (size_t)n * 64 + q * 8);
        op[0] = make_float4(e8[0] * inv2, e8[1] * inv2, e8[2] * inv2, e8[3] * inv2);
        op[1] = make_float4(e8[4] * inv2, e8[5] * inv2, e8[6] * inv2, e8[7] * inv2);
    }
}

// ---------------- launcher ----------------
extern "C" void kernel_launch(void* const* d_in, const int* in_sizes, int n_in,
                              void* d_out, int out_size, void* d_ws, size_t ws_size,
                              hipStream_t stream) {
    const float* X   = (const float*)d_in[0];
    const float* W1  = (const float*)d_in[1];
    const float* a1s = (const float*)d_in[2];
    const float* a1d = (const float*)d_in[3];
    const float* W2  = (const float*)d_in[4];
    const float* a2s = (const float*)d_in[5];
    const float* a2d = (const float*)d_in[6];
    const int*   src = (const int*)d_in[7];
    const int*   dst = (const int*)d_in[8];
    float* out = (float*)d_out;

    char* w = (char*)d_ws;
    size_t off = 0;
    auto alloc = [&](size_t bytes) {
        void* p = w + off;
        off += (bytes + 255) & ~(size_t)255;
        return p;
    };
    unsigned short* Bh = (unsigned short*)alloc((size_t)C1 * F_IN * 2);
    unsigned short* Bl = (unsigned short*)alloc((size_t)C1 * F_IN * 2);
    float* WH    = (float*)alloc((size_t)N_NODES * 64 * 4);  // Wh1, later reused as Wh2
    float* h2    = (float*)alloc((size_t)N_NODES * 64 * 4);
    float* es1   = (float*)alloc((size_t)N_NODES * 8 * 4);
    float* ed1   = (float*)alloc((size_t)N_NODES * 8 * 4);
    float* es2   = (float*)alloc((size_t)N_NODES * 4);
    float* ed2   = (float*)alloc((size_t)N_NODES * 4);
    int*   deg   = (int*)alloc((size_t)N_NODES * 4);
    int*   fill  = (int*)alloc((size_t)N_NODES * 4);
    int*   rowptr= (int*)alloc((size_t)N_NODES * 4);
    int*   col   = (int*)alloc((size_t)N_EDGES * 4);
    int*   bsums = (int*)alloc(256 * 4);
    int*   boffs = (int*)alloc(256 * 4);

    hipMemsetAsync(deg, 0, (size_t)N_NODES * 4, stream);
    hipMemsetAsync(fill, 0, (size_t)N_NODES * 4, stream);

    // CSR build
    k_hist<<<(N_EDGES + 255) / 256, 256, 0, stream>>>(dst, deg);
    k_scan1<<<NBLK_SCAN, 256, 0, stream>>>(deg, rowptr, bsums);
    k_scan2<<<1, 256, 0, stream>>>(bsums, boffs);
    k_scan3<<<NBLK_SCAN, 256, 0, stream>>>(rowptr, boffs);
    k_scatter<<<(N_EDGES + 255) / 256, 256, 0, stream>>>(src, dst, rowptr, fill, col);

    // layer 1
    k_wt<<<(C1 * F_IN + 255) / 256, 256, 0, stream>>>(W1, Bh, Bl);
    k_gemm1<<<N_NODES / 16, 64, 0, stream>>>(X, Bh, Bl, WH);
    k_esed1<<<(N_NODES * H1 + 255) / 256, 256, 0, stream>>>(WH, a1s, a1d, es1, ed1);
    k_agg1<<<(N_NODES + 3) / 4, 256, 0, stream>>>(WH, es1, ed1, rowptr, deg, col, h2);

    // layer 2 (WH reused as Wh2)
    k_gemm2<<<(N_NODES + 3) / 4, 256, 0, stream>>>(h2, W2, a2s, a2d, WH, es2, ed2);
    k_agg2<<<(N_NODES + 3) / 4, 256, 0, stream>>>(WH, es2, ed2, rowptr, deg, col, out);
}

// Round 3
// 398.056 us; speedup vs baseline: 1.1394x; 1.0218x over previous
//
#include <hip/hip_runtime.h>
#include <math.h>

#define N_NODES 50000
#define N_EDGES 800000
#define F_IN    512
#define H1      8
#define F_HID   8
#define C1      64      // H1*F_HID
#define NLAB    64
#define SLOPE   0.2f

#define NBLK_SCAN 196   // ceil(50000/256)

typedef __attribute__((ext_vector_type(8))) short short8;
typedef __attribute__((ext_vector_type(4))) float f32x4;

// ---------------- W1 -> B^T bf16 hi/lo: Bh/Bl[c][f], c=0..63, f=0..511 ----------------
__global__ void k_wt(const float* __restrict__ W1, unsigned short* __restrict__ Bh,
                     unsigned short* __restrict__ Bl) {
    int i = blockIdx.x * 256 + threadIdx.x;
    if (i >= C1 * F_IN) return;
    int c = i >> 9, f = i & 511;
    float v = W1[(c >> 3) * (F_IN * F_HID) + f * F_HID + (c & 7)];
    unsigned bits = __float_as_uint(v);
    unsigned hb = bits & 0xFFFF0000u;
    float r = v - __uint_as_float(hb);
    Bh[i] = (unsigned short)(bits >> 16);
    Bl[i] = (unsigned short)(__float_as_uint(r) >> 16);
}

// ---------------- GEMM1 via bf16-split MFMA ----------------
// 2 waves per 16-row group (32 cols each) -> 6250 single-wave blocks, ~24 waves/CU.
__launch_bounds__(64)
__global__ void k_gemm1(const float* __restrict__ X, const unsigned short* __restrict__ Bh,
                        const unsigned short* __restrict__ Bl, float* __restrict__ Wh) {
    const int lane = threadIdx.x;
    const int rg = blockIdx.x >> 1;
    const int half = blockIdx.x & 1;
    const int r0 = rg * 16;
    const int m = lane & 15;          // A row / C col index
    const int quad = lane >> 4;       // k-octet selector
    const float* xrow = X + (size_t)(r0 + m) * F_IN + quad * 8;

    f32x4 acc[2] = {};                // 2 n-subtiles of 16 cols

    #pragma unroll 4
    for (int kt = 0; kt < F_IN; kt += 32) {
        float4 xa = *(const float4*)(xrow + kt);
        float4 xb = *(const float4*)(xrow + kt + 4);
        float xs[8] = {xa.x, xa.y, xa.z, xa.w, xb.x, xb.y, xb.z, xb.w};
        short8 ah, al;
        #pragma unroll
        for (int j = 0; j < 8; j++) {
            unsigned bits = __float_as_uint(xs[j]);
            float r = xs[j] - __uint_as_float(bits & 0xFFFF0000u);
            ah[j] = (short)(bits >> 16);
            al[j] = (short)(__float_as_uint(r) >> 16);
        }
        #pragma unroll
        for (int si = 0; si < 2; si++) {
            const int s = half * 2 + si;
            const size_t boff = (size_t)(s * 16 + m) * F_IN + kt + quad * 8;
            short8 bh = *(const short8*)(Bh + boff);
            short8 bl = *(const short8*)(Bl + boff);
            acc[si] = __builtin_amdgcn_mfma_f32_16x16x32_bf16(al, bh, acc[si], 0, 0, 0);
            acc[si] = __builtin_amdgcn_mfma_f32_16x16x32_bf16(ah, bl, acc[si], 0, 0, 0);
            acc[si] = __builtin_amdgcn_mfma_f32_16x16x32_bf16(ah, bh, acc[si], 0, 0, 0);
        }
    }
    // C/D: col = lane&15 (within subtile), row = quad*4 + reg
    #pragma unroll
    for (int si = 0; si < 2; si++)
        #pragma unroll
        for (int reg = 0; reg < 4; reg++)
            Wh[(size_t)(r0 + quad * 4 + reg) * 64 + (half * 2 + si) * 16 + m] = acc[si][reg];
}

// ---------------- es/ed for layer 1 ----------------
__global__ void k_esed1(const float* __restrict__ Wh, const float* __restrict__ a_s,
                        const float* __restrict__ a_d, float* __restrict__ es,
                        float* __restrict__ ed) {
    int i = blockIdx.x * 256 + threadIdx.x;
    if (i >= N_NODES * H1) return;
    int n = i >> 3, h = i & 7;
    const float* w = Wh + (size_t)n * 64 + h * 8;
    float s = 0.f, d = 0.f;
    #pragma unroll
    for (int j = 0; j < 8; j++) {
        float v = w[j];
        s += v * a_s[h * 8 + j];
        d += v * a_d[h * 8 + j];
    }
    es[i] = s;
    ed[i] = d;
}

// ---------------- CSR build ----------------
__global__ void k_hist(const int* __restrict__ dst, int* __restrict__ deg) {
    int e = blockIdx.x * 256 + threadIdx.x;
    if (e < N_EDGES) atomicAdd(&deg[dst[e]], 1);
}

__global__ void k_scan1(const int* __restrict__ deg, int* __restrict__ rowptr,
                        int* __restrict__ bsums) {
    __shared__ int s[256];
    int t = threadIdx.x;
    int g = blockIdx.x * 256 + t;
    int v = (g < N_NODES) ? deg[g] : 0;
    s[t] = v;
    __syncthreads();
    #pragma unroll
    for (int off = 1; off < 256; off <<= 1) {
        int a = s[t];
        int b = (t >= off) ? s[t - off] : 0;
        __syncthreads();
        s[t] = a + b;
        __syncthreads();
    }
    if (g < N_NODES) rowptr[g] = s[t] - v;
    if (t == 255) bsums[blockIdx.x] = s[t];
}

__global__ void k_scan2(const int* __restrict__ bsums, int* __restrict__ boffs) {
    __shared__ int s[256];
    int t = threadIdx.x;
    int v = (t < NBLK_SCAN) ? bsums[t] : 0;
    s[t] = v;
    __syncthreads();
    #pragma unroll
    for (int off = 1; off < 256; off <<= 1) {
        int a = s[t];
        int b = (t >= off) ? s[t - off] : 0;
        __syncthreads();
        s[t] = a + b;
        __syncthreads();
    }
    if (t < NBLK_SCAN) boffs[t] = s[t] - v;
}

__global__ void k_scan3(int* __restrict__ rowptr, const int* __restrict__ boffs) {
    int g = blockIdx.x * 256 + threadIdx.x;
    if (g < N_NODES) rowptr[g] += boffs[blockIdx.x];
}

__global__ void k_scatter(const int* __restrict__ src, const int* __restrict__ dst,
                          const int* __restrict__ rowptr, int* __restrict__ fill,
                          int* __restrict__ col) {
    int e = blockIdx.x * 256 + threadIdx.x;
    if (e >= N_EDGES) return;
    int d = dst[e];
    int pos = rowptr[d] + atomicAdd(&fill[d], 1);
    col[pos] = src[e];
}

// ---------------- layer-1 attention aggregation (single pass, no max) ----------------
// Scores are O(1) so exp() cannot overflow; softmax is shift-invariant -> identical result.
// wave per node; lane = g*8+q: group g handles edges e===g (mod 8), lane holds
// head q / channels 8q..8q+7.
__launch_bounds__(256)
__global__ void k_agg1(const float* __restrict__ Wh, const float* __restrict__ es,
                       const float* __restrict__ ed, const int* __restrict__ rowptr,
                       const int* __restrict__ deg, const int* __restrict__ col,
                       float* __restrict__ h2) {
    int wv = threadIdx.x >> 6, lane = threadIdx.x & 63;
    int n = blockIdx.x * 4 + wv;
    if (n >= N_NODES) return;
    int start = rowptr[n], d = deg[n];
    int g = lane >> 3, q = lane & 7;
    float edq = ed[n * 8 + q];

    float den = 0.f;
    float acc[8] = {};
    #pragma unroll 2
    for (int base = 0; base < d; base += 8) {
        int e = base + g;
        if (e < d) {
            int sv = col[start + e];
            float x = es[sv * 8 + q] + edq;
            x = x > 0.f ? x : SLOPE * x;
            float w = __expf(x);
            den += w;
            const float* wp = Wh + (size_t)sv * 64 + q * 8;
            float4 v0 = *(const float4*)(wp);
            float4 v1 = *(const float4*)(wp + 4);
            acc[0] += w * v0.x; acc[1] += w * v0.y; acc[2] += w * v0.z; acc[3] += w * v0.w;
            acc[4] += w * v1.x; acc[5] += w * v1.y; acc[6] += w * v1.z; acc[7] += w * v1.w;
        }
    }
    #pragma unroll
    for (int off = 8; off <= 32; off <<= 1) {
        den += __shfl_xor(den, off);
        #pragma unroll
        for (int j = 0; j < 8; j++) acc[j] += __shfl_xor(acc[j], off);
    }
    if (g == 0) {
        float inv = 1.f / (den + 1e-10f);
        float o[8];
        #pragma unroll
        for (int j = 0; j < 8; j++) {
            float v = acc[j] * inv;
            o[j] = v > 0.f ? v : expm1f(v);   // fused ELU
        }
        float4* hp = (float4*)(h2 + (size_t)n * 64 + q * 8);
        hp[0] = make_float4(o[0], o[1], o[2], o[3]);
        hp[1] = make_float4(o[4], o[5], o[6], o[7]);
    }
}

// ---------------- GEMM2 (K=64), 16 nodes/block + fused es2/ed2 epilogue ----------------
__launch_bounds__(256)
__global__ void k_gemm2(const float* __restrict__ h2, const float* __restrict__ W2,
                        const float* __restrict__ a2s, const float* __restrict__ a2d,
                        float* __restrict__ Wh2, float* __restrict__ es2,
                        float* __restrict__ ed2) {
    __shared__ float Ws[64 * 64];
    __shared__ float hs[16][64];
    int t = threadIdx.x;
    int n0 = blockIdx.x * 16;
    #pragma unroll
    for (int i = 0; i < 4; i++) {
        int flat = i * 256 + t;
        *(float4*)(Ws + flat * 4) = *(const float4*)(W2 + flat * 4);
    }
    #pragma unroll
    for (int i = 0; i < 4; i++) {
        int flat = i * 256 + t;           // 0..1023
        hs[flat >> 6][flat & 63] = h2[(size_t)(n0 + (flat >> 6)) * 64 + (flat & 63)];
    }
    __syncthreads();
    int wv = t >> 6, lane = t & 63;
    float as = a2s[lane], ad = a2d[lane];
    #pragma unroll
    for (int j = 0; j < 4; j++) {
        int nl = wv * 4 + j;
        int n = n0 + nl;
        float acc = 0.f;
        #pragma unroll
        for (int k = 0; k < 64; k++) acc += hs[nl][k] * Ws[k * 64 + lane];
        Wh2[(size_t)n * 64 + lane] = acc;
        float s = acc * as;
        float dd = acc * ad;
        #pragma unroll
        for (int off = 1; off < 64; off <<= 1) {
            s += __shfl_xor(s, off);
            dd += __shfl_xor(dd, off);
        }
        if (lane == 0) { es2[n] = s; ed2[n] = dd; }
    }
}

// ---------------- layer-2 aggregation (single pass) + fused final softmax ----------------
__launch_bounds__(256)
__global__ void k_agg2(const float* __restrict__ Wh2, const float* __restrict__ es2,
                       const float* __restrict__ ed2, const int* __restrict__ rowptr,
                       const int* __restrict__ deg, const int* __restrict__ col,
                       float* __restrict__ out) {
    int wv = threadIdx.x >> 6, lane = threadIdx.x & 63;
    int n = blockIdx.x * 4 + wv;
    if (n >= N_NODES) return;
    int start = rowptr[n], d = deg[n];
    int g = lane >> 3, q = lane & 7;
    float edn = ed2[n];

    float den = 0.f;
    float acc[8] = {};
    #pragma unroll 2
    for (int base = 0; base < d; base += 8) {
        int e = base + g;
        if (e < d) {
            int sv = col[start + e];
            float x = es2[sv] + edn;
            x = x > 0.f ? x : SLOPE * x;
            float w = __expf(x);
            den += w;
            const float* wp = Wh2 + (size_t)sv * 64 + q * 8;
            float4 v0 = *(const float4*)(wp);
            float4 v1 = *(const float4*)(wp + 4);
            acc[0] += w * v0.x; acc[1] += w * v0.y; acc[2] += w * v0.z; acc[3] += w * v0.w;
            acc[4] += w * v1.x; acc[5] += w * v1.y; acc[6] += w * v1.z; acc[7] += w * v1.w;
        }
    }
    #pragma unroll
    for (int off = 8; off <= 32; off <<= 1) {
        den += __shfl_xor(den, off);
        #pragma unroll
        for (int j = 0; j < 8; j++) acc[j] += __shfl_xor(acc[j], off);
    }
    float inv = 1.f / (den + 1e-10f);
    float o[8];
    #pragma unroll
    for (int j = 0; j < 8; j++) o[j] = acc[j] * inv;
    // fused softmax over 64 classes: lane q holds channels 8q..8q+7 (all g duplicate)
    float mx = o[0];
    #pragma unroll
    for (int j = 1; j < 8; j++) mx = fmaxf(mx, o[j]);
    mx = fmaxf(mx, __shfl_xor(mx, 1));
    mx = fmaxf(mx, __shfl_xor(mx, 2));
    mx = fmaxf(mx, __shfl_xor(mx, 4));
    float e8[8], sm = 0.f;
    #pragma unroll
    for (int j = 0; j < 8; j++) { e8[j] = __expf(o[j] - mx); sm += e8[j]; }
    sm += __shfl_xor(sm, 1);
    sm += __shfl_xor(sm, 2);
    sm += __shfl_xor(sm, 4);
    if (g == 0) {
        float inv2 = 1.f / sm;
        float4* op = (float4*)(out + (size_t)n * 64 + q * 8);
        op[0] = make_float4(e8[0] * inv2, e8[1] * inv2, e8[2] * inv2, e8[3] * inv2);
        op[1] = make_float4(e8[4] * inv2, e8[5] * inv2, e8[6] * inv2, e8[7] * inv2);
    }
}

// ---------------- launcher ----------------
extern "C" void kernel_launch(void* const* d_in, const int* in_sizes, int n_in,
                              void* d_out, int out_size, void* d_ws, size_t ws_size,
                              hipStream_t stream) {
    const float* X   = (const float*)d_in[0];
    const float* W1  = (const float*)d_in[1];
    const float* a1s = (const float*)d_in[2];
    const float* a1d = (const float*)d_in[3];
    const float* W2  = (const float*)d_in[4];
    const float* a2s = (const float*)d_in[5];
    const float* a2d = (const float*)d_in[6];
    const int*   src = (const int*)d_in[7];
    const int*   dst = (const int*)d_in[8];
    float* out = (float*)d_out;

    char* w = (char*)d_ws;
    size_t off = 0;
    auto alloc = [&](size_t bytes) {
        void* p = w + off;
        off += (bytes + 255) & ~(size_t)255;
        return p;
    };
    unsigned short* Bh = (unsigned short*)alloc((size_t)C1 * F_IN * 2);
    unsigned short* Bl = (unsigned short*)alloc((size_t)C1 * F_IN * 2);
    float* WH    = (float*)alloc((size_t)N_NODES * 64 * 4);  // Wh1, later reused as Wh2
    float* h2    = (float*)alloc((size_t)N_NODES * 64 * 4);
    float* es1   = (float*)alloc((size_t)N_NODES * 8 * 4);
    float* ed1   = (float*)alloc((size_t)N_NODES * 8 * 4);
    float* es2   = (float*)alloc((size_t)N_NODES * 4);
    float* ed2   = (float*)alloc((size_t)N_NODES * 4);
    int*   deg   = (int*)alloc((size_t)N_NODES * 4);
    int*   fill  = (int*)alloc((size_t)N_NODES * 4);
    int*   rowptr= (int*)alloc((size_t)N_NODES * 4);
    int*   col   = (int*)alloc((size_t)N_EDGES * 4);
    int*   bsums = (int*)alloc(256 * 4);
    int*   boffs = (int*)alloc(256 * 4);

    hipMemsetAsync(deg, 0, (size_t)N_NODES * 4, stream);
    hipMemsetAsync(fill, 0, (size_t)N_NODES * 4, stream);

    // CSR build
    k_hist<<<(N_EDGES + 255) / 256, 256, 0, stream>>>(dst, deg);
    k_scan1<<<NBLK_SCAN, 256, 0, stream>>>(deg, rowptr, bsums);
    k_scan2<<<1, 256, 0, stream>>>(bsums, boffs);
    k_scan3<<<NBLK_SCAN, 256, 0, stream>>>(rowptr, boffs);
    k_scatter<<<(N_EDGES + 255) / 256, 256, 0, stream>>>(src, dst, rowptr, fill, col);

    // layer 1
    k_wt<<<(C1 * F_IN + 255) / 256, 256, 0, stream>>>(W1, Bh, Bl);
    k_gemm1<<<(N_NODES / 16) * 2, 64, 0, stream>>>(X, Bh, Bl, WH);
    k_esed1<<<(N_NODES * H1 + 255) / 256, 256, 0, stream>>>(WH, a1s, a1d, es1, ed1);
    k_agg1<<<(N_NODES + 3) / 4, 256, 0, stream>>>(WH, es1, ed1, rowptr, deg, col, h2);

    // layer 2 (WH reused as Wh2)
    k_gemm2<<<N_NODES / 16, 256, 0, stream>>>(h2, W2, a2s, a2d, WH, es2, ed2);
    k_agg2<<<(N_NODES + 3) / 4, 256, 0, stream>>>(WH, es2, ed2, rowptr, deg, col, out);
}

// Round 4
// 364.280 us; speedup vs baseline: 1.2451x; 1.0927x over previous
//
#include <hip/hip_runtime.h>
#include <math.h>

#define N_NODES 50000
#define N_EDGES 800000
#define F_IN    512
#define H1      8
#define F_HID   8
#define C1      64      // H1*F_HID
#define NLAB    64
#define SLOPE   0.2f

#define NBLK_SCAN 196   // ceil(50000/256)

typedef __attribute__((ext_vector_type(8))) short short8;
typedef __attribute__((ext_vector_type(4))) float f32x4;

__device__ __forceinline__ float bf_lo(unsigned u) { return __uint_as_float(u << 16); }
__device__ __forceinline__ float bf_hi(unsigned u) { return __uint_as_float(u & 0xFFFF0000u); }
__device__ __forceinline__ unsigned short f2bf(float x) {
    unsigned bits = __float_as_uint(x);
    return (unsigned short)((bits + 0x7FFF + ((bits >> 16) & 1)) >> 16);   // RNE
}

// ---------------- W1 -> B^T bf16 hi/lo: Bh/Bl[c][f], c=0..63, f=0..511 ----------------
__global__ void k_wt(const float* __restrict__ W1, unsigned short* __restrict__ Bh,
                     unsigned short* __restrict__ Bl) {
    int i = blockIdx.x * 256 + threadIdx.x;
    if (i >= C1 * F_IN) return;
    int c = i >> 9, f = i & 511;
    float v = W1[(c >> 3) * (F_IN * F_HID) + f * F_HID + (c & 7)];
    unsigned bits = __float_as_uint(v);
    unsigned hb = bits & 0xFFFF0000u;
    float r = v - __uint_as_float(hb);
    Bh[i] = (unsigned short)(bits >> 16);
    Bl[i] = (unsigned short)(__float_as_uint(r) >> 16);
}

// ---------------- GEMM1: X[50000,512] @ W[512,64] -> Wh bf16 ----------------
// 256 thr / 4 waves / 64 rows / 64 cols per block. B hi/lo in LDS per K-chunk of 128.
// X read once (each row belongs to exactly one block), depth-1 prefetch.
__launch_bounds__(256)
__global__ void k_gemm1(const float* __restrict__ X, const unsigned short* __restrict__ Bh,
                        const unsigned short* __restrict__ Bl, unsigned short* __restrict__ Wh) {
    __shared__ unsigned short sBh[64][136];   // [col][k] pad 8 -> 2-way banks (free)
    __shared__ unsigned short sBl[64][136];
    const int t = threadIdx.x;
    const int lane = t & 63, w = t >> 6;
    const int r0 = blockIdx.x * 64 + w * 16;
    const int m = lane & 15, quad = lane >> 4;
    int row = r0 + m; if (row >= N_NODES) row = N_NODES - 1;
    const float* xrow = X + (size_t)row * F_IN + quad * 8;

    const int sc = t >> 2;        // staging col 0..63
    const int sp = t & 3;         // staging quarter 0..3

    f32x4 acc[4] = {};
    float4 xa = *(const float4*)(xrow);
    float4 xb = *(const float4*)(xrow + 4);

    for (int chunk = 0; chunk < 4; chunk++) {
        const int k0 = chunk * 128;
        if (chunk) __syncthreads();           // previous chunk's reads done
        #pragma unroll
        for (int i = 0; i < 4; i++) {
            const unsigned short* gh = Bh + sc * F_IN + k0 + sp * 32 + i * 8;
            const unsigned short* gl = Bl + sc * F_IN + k0 + sp * 32 + i * 8;
            *(short8*)(&sBh[sc][sp * 32 + i * 8]) = *(const short8*)gh;
            *(short8*)(&sBl[sc][sp * 32 + i * 8]) = *(const short8*)gl;
        }
        __syncthreads();
        #pragma unroll
        for (int i = 0; i < 4; i++) {
            const int ktn = (k0 + i * 32 + 32) & 511;   // wraps harmlessly on last iter
            float4 na = *(const float4*)(xrow + ktn);
            float4 nb = *(const float4*)(xrow + ktn + 4);
            float xs[8] = {xa.x, xa.y, xa.z, xa.w, xb.x, xb.y, xb.z, xb.w};
            short8 ah, al;
            #pragma unroll
            for (int j = 0; j < 8; j++) {
                unsigned bits = __float_as_uint(xs[j]);
                float r = xs[j] - __uint_as_float(bits & 0xFFFF0000u);
                ah[j] = (short)(bits >> 16);
                al[j] = (short)(__float_as_uint(r) >> 16);
            }
            #pragma unroll
            for (int s = 0; s < 4; s++) {
                short8 bh = *(const short8*)(&sBh[s * 16 + m][i * 32 + quad * 8]);
                short8 bl = *(const short8*)(&sBl[s * 16 + m][i * 32 + quad * 8]);
                acc[s] = __builtin_amdgcn_mfma_f32_16x16x32_bf16(al, bh, acc[s], 0, 0, 0);
                acc[s] = __builtin_amdgcn_mfma_f32_16x16x32_bf16(ah, bl, acc[s], 0, 0, 0);
                acc[s] = __builtin_amdgcn_mfma_f32_16x16x32_bf16(ah, bh, acc[s], 0, 0, 0);
            }
            xa = na; xb = nb;
        }
    }
    // C/D: col = s*16+m, row = quad*4+reg
    #pragma unroll
    for (int s = 0; s < 4; s++)
        #pragma unroll
        for (int reg = 0; reg < 4; reg++) {
            int gr = r0 + quad * 4 + reg;
            if (gr < N_NODES)
                Wh[(size_t)gr * 64 + s * 16 + m] = f2bf(acc[s][reg]);
        }
}

// ---------------- es/ed for layer 1 (bf16 Wh input) ----------------
__global__ void k_esed1(const unsigned short* __restrict__ Wh, const float* __restrict__ a_s,
                        const float* __restrict__ a_d, float* __restrict__ es,
                        float* __restrict__ ed) {
    int i = blockIdx.x * 256 + threadIdx.x;
    if (i >= N_NODES * H1) return;
    int n = i >> 3, h = i & 7;
    uint4 u = *(const uint4*)(Wh + (size_t)n * 64 + h * 8);
    float v[8] = {bf_lo(u.x), bf_hi(u.x), bf_lo(u.y), bf_hi(u.y),
                  bf_lo(u.z), bf_hi(u.z), bf_lo(u.w), bf_hi(u.w)};
    float s = 0.f, d = 0.f;
    #pragma unroll
    for (int j = 0; j < 8; j++) {
        s += v[j] * a_s[h * 8 + j];
        d += v[j] * a_d[h * 8 + j];
    }
    es[i] = s;
    ed[i] = d;
}

// ---------------- CSR build ----------------
__global__ void k_hist(const int* __restrict__ dst, int* __restrict__ deg) {
    int e = blockIdx.x * 256 + threadIdx.x;
    if (e < N_EDGES) atomicAdd(&deg[dst[e]], 1);
}

__global__ void k_scan1(const int* __restrict__ deg, int* __restrict__ rowptr,
                        int* __restrict__ bsums) {
    __shared__ int s[256];
    int t = threadIdx.x;
    int g = blockIdx.x * 256 + t;
    int v = (g < N_NODES) ? deg[g] : 0;
    s[t] = v;
    __syncthreads();
    #pragma unroll
    for (int off = 1; off < 256; off <<= 1) {
        int a = s[t];
        int b = (t >= off) ? s[t - off] : 0;
        __syncthreads();
        s[t] = a + b;
        __syncthreads();
    }
    if (g < N_NODES) rowptr[g] = s[t] - v;
    if (t == 255) bsums[blockIdx.x] = s[t];
}

__global__ void k_scan2(const int* __restrict__ bsums, int* __restrict__ boffs) {
    __shared__ int s[256];
    int t = threadIdx.x;
    int v = (t < NBLK_SCAN) ? bsums[t] : 0;
    s[t] = v;
    __syncthreads();
    #pragma unroll
    for (int off = 1; off < 256; off <<= 1) {
        int a = s[t];
        int b = (t >= off) ? s[t - off] : 0;
        __syncthreads();
        s[t] = a + b;
        __syncthreads();
    }
    if (t < NBLK_SCAN) boffs[t] = s[t] - v;
}

__global__ void k_scan3(int* __restrict__ rowptr, const int* __restrict__ boffs) {
    int g = blockIdx.x * 256 + threadIdx.x;
    if (g < N_NODES) rowptr[g] += boffs[blockIdx.x];
}

__global__ void k_scatter(const int* __restrict__ src, const int* __restrict__ dst,
                          const int* __restrict__ rowptr, int* __restrict__ fill,
                          int* __restrict__ col) {
    int e = blockIdx.x * 256 + threadIdx.x;
    if (e >= N_EDGES) return;
    int d = dst[e];
    int pos = rowptr[d] + atomicAdd(&fill[d], 1);
    col[pos] = src[e];
}

// ---------------- layer-1 aggregation: single pass (no max), bf16 Wh, 2x edge unroll ----
__launch_bounds__(256)
__global__ void k_agg1(const unsigned short* __restrict__ Wh, const float* __restrict__ es,
                       const float* __restrict__ ed, const int* __restrict__ rowptr,
                       const int* __restrict__ deg, const int* __restrict__ col,
                       float* __restrict__ h2) {
    int wv = threadIdx.x >> 6, lane = threadIdx.x & 63;
    int n = blockIdx.x * 4 + wv;
    if (n >= N_NODES) return;
    int start = rowptr[n], d = deg[n];
    int g = lane >> 3, q = lane & 7;
    float edq = ed[n * 8 + q];

    float den = 0.f;
    float acc[8] = {};
    for (int base = 0; base < d; base += 16) {
        int e0 = base + g, e1 = base + 8 + g;
        int sv0 = col[start + min(e0, d - 1)];
        int sv1 = col[start + min(e1, d - 1)];
        float x0 = es[sv0 * 8 + q] + edq;
        float x1 = es[sv1 * 8 + q] + edq;
        uint4 u0 = *(const uint4*)(Wh + (size_t)sv0 * 64 + q * 8);
        uint4 u1 = *(const uint4*)(Wh + (size_t)sv1 * 64 + q * 8);
        x0 = x0 > 0.f ? x0 : SLOPE * x0;
        x1 = x1 > 0.f ? x1 : SLOPE * x1;
        float w0 = (e0 < d) ? __expf(x0) : 0.f;
        float w1 = (e1 < d) ? __expf(x1) : 0.f;
        den += w0 + w1;
        float f0[8] = {bf_lo(u0.x), bf_hi(u0.x), bf_lo(u0.y), bf_hi(u0.y),
                       bf_lo(u0.z), bf_hi(u0.z), bf_lo(u0.w), bf_hi(u0.w)};
        float f1[8] = {bf_lo(u1.x), bf_hi(u1.x), bf_lo(u1.y), bf_hi(u1.y),
                       bf_lo(u1.z), bf_hi(u1.z), bf_lo(u1.w), bf_hi(u1.w)};
        #pragma unroll
        for (int j = 0; j < 8; j++) acc[j] += w0 * f0[j] + w1 * f1[j];
    }
    #pragma unroll
    for (int off = 8; off <= 32; off <<= 1) {
        den += __shfl_xor(den, off);
        #pragma unroll
        for (int j = 0; j < 8; j++) acc[j] += __shfl_xor(acc[j], off);
    }
    if (g == 0) {
        float inv = 1.f / (den + 1e-10f);
        float o[8];
        #pragma unroll
        for (int j = 0; j < 8; j++) {
            float v = acc[j] * inv;
            o[j] = v > 0.f ? v : expm1f(v);   // fused ELU
        }
        float4* hp = (float4*)(h2 + (size_t)n * 64 + q * 8);
        hp[0] = make_float4(o[0], o[1], o[2], o[3]);
        hp[1] = make_float4(o[4], o[5], o[6], o[7]);
    }
}

// ---------------- GEMM2 (K=64), 16 nodes/block; Wh2 bf16 out; es2/ed2 from fp32 acc ----
__launch_bounds__(256)
__global__ void k_gemm2(const float* __restrict__ h2, const float* __restrict__ W2,
                        const float* __restrict__ a2s, const float* __restrict__ a2d,
                        unsigned short* __restrict__ Wh2, float* __restrict__ es2,
                        float* __restrict__ ed2) {
    __shared__ float Ws[64 * 64];
    __shared__ float hs[16][64];
    int t = threadIdx.x;
    int n0 = blockIdx.x * 16;
    #pragma unroll
    for (int i = 0; i < 4; i++) {
        int flat = i * 256 + t;
        *(float4*)(Ws + flat * 4) = *(const float4*)(W2 + flat * 4);
    }
    #pragma unroll
    for (int i = 0; i < 4; i++) {
        int flat = i * 256 + t;
        hs[flat >> 6][flat & 63] = h2[(size_t)(n0 + (flat >> 6)) * 64 + (flat & 63)];
    }
    __syncthreads();
    int wv = t >> 6, lane = t & 63;
    float as = a2s[lane], ad = a2d[lane];
    #pragma unroll
    for (int j = 0; j < 4; j++) {
        int nl = wv * 4 + j;
        int n = n0 + nl;
        float acc = 0.f;
        #pragma unroll
        for (int k = 0; k < 64; k++) acc += hs[nl][k] * Ws[k * 64 + lane];
        Wh2[(size_t)n * 64 + lane] = f2bf(acc);
        float s = acc * as;
        float dd = acc * ad;
        #pragma unroll
        for (int off = 1; off < 64; off <<= 1) {
            s += __shfl_xor(s, off);
            dd += __shfl_xor(dd, off);
        }
        if (lane == 0) { es2[n] = s; ed2[n] = dd; }
    }
}

// ---------------- layer-2 aggregation (bf16 Wh2, 2x unroll) + fused final softmax ------
__launch_bounds__(256)
__global__ void k_agg2(const unsigned short* __restrict__ Wh2, const float* __restrict__ es2,
                       const float* __restrict__ ed2, const int* __restrict__ rowptr,
                       const int* __restrict__ deg, const int* __restrict__ col,
                       float* __restrict__ out) {
    int wv = threadIdx.x >> 6, lane = threadIdx.x & 63;
    int n = blockIdx.x * 4 + wv;
    if (n >= N_NODES) return;
    int start = rowptr[n], d = deg[n];
    int g = lane >> 3, q = lane & 7;
    float edn = ed2[n];

    float den = 0.f;
    float acc[8] = {};
    for (int base = 0; base < d; base += 16) {
        int e0 = base + g, e1 = base + 8 + g;
        int sv0 = col[start + min(e0, d - 1)];
        int sv1 = col[start + min(e1, d - 1)];
        float x0 = es2[sv0] + edn;
        float x1 = es2[sv1] + edn;
        uint4 u0 = *(const uint4*)(Wh2 + (size_t)sv0 * 64 + q * 8);
        uint4 u1 = *(const uint4*)(Wh2 + (size_t)sv1 * 64 + q * 8);
        x0 = x0 > 0.f ? x0 : SLOPE * x0;
        x1 = x1 > 0.f ? x1 : SLOPE * x1;
        float w0 = (e0 < d) ? __expf(x0) : 0.f;
        float w1 = (e1 < d) ? __expf(x1) : 0.f;
        den += w0 + w1;
        float f0[8] = {bf_lo(u0.x), bf_hi(u0.x), bf_lo(u0.y), bf_hi(u0.y),
                       bf_lo(u0.z), bf_hi(u0.z), bf_lo(u0.w), bf_hi(u0.w)};
        float f1[8] = {bf_lo(u1.x), bf_hi(u1.x), bf_lo(u1.y), bf_hi(u1.y),
                       bf_lo(u1.z), bf_hi(u1.z), bf_lo(u1.w), bf_hi(u1.w)};
        #pragma unroll
        for (int j = 0; j < 8; j++) acc[j] += w0 * f0[j] + w1 * f1[j];
    }
    #pragma unroll
    for (int off = 8; off <= 32; off <<= 1) {
        den += __shfl_xor(den, off);
        #pragma unroll
        for (int j = 0; j < 8; j++) acc[j] += __shfl_xor(acc[j], off);
    }
    float inv = 1.f / (den + 1e-10f);
    float o[8];
    #pragma unroll
    for (int j = 0; j < 8; j++) o[j] = acc[j] * inv;
    // fused softmax over 64 classes: lane q holds channels 8q..8q+7 (all g duplicate)
    float mx = o[0];
    #pragma unroll
    for (int j = 1; j < 8; j++) mx = fmaxf(mx, o[j]);
    mx = fmaxf(mx, __shfl_xor(mx, 1));
    mx = fmaxf(mx, __shfl_xor(mx, 2));
    mx = fmaxf(mx, __shfl_xor(mx, 4));
    float e8[8], sm = 0.f;
    #pragma unroll
    for (int j = 0; j < 8; j++) { e8[j] = __expf(o[j] - mx); sm += e8[j]; }
    sm += __shfl_xor(sm, 1);
    sm += __shfl_xor(sm, 2);
    sm += __shfl_xor(sm, 4);
    if (g == 0) {
        float inv2 = 1.f / sm;
        float4* op = (float4*)(out + (size_t)n * 64 + q * 8);
        op[0] = make_float4(e8[0] * inv2, e8[1] * inv2, e8[2] * inv2, e8[3] * inv2);
        op[1] = make_float4(e8[4] * inv2, e8[5] * inv2, e8[6] * inv2, e8[7] * inv2);
    }
}

// ---------------- launcher ----------------
extern "C" void kernel_launch(void* const* d_in, const int* in_sizes, int n_in,
                              void* d_out, int out_size, void* d_ws, size_t ws_size,
                              hipStream_t stream) {
    const float* X   = (const float*)d_in[0];
    const float* W1  = (const float*)d_in[1];
    const float* a1s = (const float*)d_in[2];
    const float* a1d = (const float*)d_in[3];
    const float* W2  = (const float*)d_in[4];
    const float* a2s = (const float*)d_in[5];
    const float* a2d = (const float*)d_in[6];
    const int*   src = (const int*)d_in[7];
    const int*   dst = (const int*)d_in[8];
    float* out = (float*)d_out;

    char* w = (char*)d_ws;
    size_t off = 0;
    auto alloc = [&](size_t bytes) {
        void* p = w + off;
        off += (bytes + 255) & ~(size_t)255;
        return p;
    };
    unsigned short* Bh  = (unsigned short*)alloc((size_t)C1 * F_IN * 2);
    unsigned short* Bl  = (unsigned short*)alloc((size_t)C1 * F_IN * 2);
    unsigned short* WH1 = (unsigned short*)alloc((size_t)N_NODES * 64 * 2);  // bf16
    unsigned short* WH2 = (unsigned short*)alloc((size_t)N_NODES * 64 * 2);  // bf16
    float* h2    = (float*)alloc((size_t)N_NODES * 64 * 4);
    float* es1   = (float*)alloc((size_t)N_NODES * 8 * 4);
    float* ed1   = (float*)alloc((size_t)N_NODES * 8 * 4);
    float* es2   = (float*)alloc((size_t)N_NODES * 4);
    float* ed2   = (float*)alloc((size_t)N_NODES * 4);
    int*   deg   = (int*)alloc((size_t)N_NODES * 4);
    int*   fill  = (int*)alloc((size_t)N_NODES * 4);
    int*   rowptr= (int*)alloc((size_t)N_NODES * 4);
    int*   col   = (int*)alloc((size_t)N_EDGES * 4);
    int*   bsums = (int*)alloc(256 * 4);
    int*   boffs = (int*)alloc(256 * 4);

    hipMemsetAsync(deg, 0, (size_t)N_NODES * 4, stream);
    hipMemsetAsync(fill, 0, (size_t)N_NODES * 4, stream);

    // CSR build
    k_hist<<<(N_EDGES + 255) / 256, 256, 0, stream>>>(dst, deg);
    k_scan1<<<NBLK_SCAN, 256, 0, stream>>>(deg, rowptr, bsums);
    k_scan2<<<1, 256, 0, stream>>>(bsums, boffs);
    k_scan3<<<NBLK_SCAN, 256, 0, stream>>>(rowptr, boffs);
    k_scatter<<<(N_EDGES + 255) / 256, 256, 0, stream>>>(src, dst, rowptr, fill, col);

    // layer 1
    k_wt<<<(C1 * F_IN + 255) / 256, 256, 0, stream>>>(W1, Bh, Bl);
    k_gemm1<<<(N_NODES + 63) / 64, 256, 0, stream>>>(X, Bh, Bl, WH1);
    k_esed1<<<(N_NODES * H1 + 255) / 256, 256, 0, stream>>>(WH1, a1s, a1d, es1, ed1);
    k_agg1<<<(N_NODES + 3) / 4, 256, 0, stream>>>(WH1, es1, ed1, rowptr, deg, col, h2);

    // layer 2
    k_gemm2<<<N_NODES / 16, 256, 0, stream>>>(h2, W2, a2s, a2d, WH2, es2, ed2);
    k_agg2<<<(N_NODES + 3) / 4, 256, 0, stream>>>(WH2, es2, ed2, rowptr, deg, col, out);
}

// Round 6
// 358.433 us; speedup vs baseline: 1.2654x; 1.0163x over previous
//
#include <hip/hip_runtime.h>
#include <math.h>

#define N_NODES 50000
#define N_EDGES 800000
#define F_IN    512
#define H1      8
#define F_HID   8
#define C1      64      // H1*F_HID
#define NLAB    64
#define SLOPE   0.2f

#define NBLK_SCAN 196   // ceil(50000/256)
#define REC1     160    // [es1: 8 f32 | Wh1: 64 bf16]
#define REC2     144    // [es2: f32, pad 12B | Wh2: 64 bf16]

typedef __attribute__((ext_vector_type(8))) short short8;
typedef __attribute__((ext_vector_type(4))) float f32x4;

__device__ __forceinline__ float bf_lo(unsigned u) { return __uint_as_float(u << 16); }
__device__ __forceinline__ float bf_hi(unsigned u) { return __uint_as_float(u & 0xFFFF0000u); }
__device__ __forceinline__ unsigned short f2bf(float x) {
    unsigned bits = __float_as_uint(x);
    return (unsigned short)((bits + 0x7FFF + ((bits >> 16) & 1)) >> 16);   // RNE
}

// ---------------- W1 -> B^T bf16 hi/lo: Bh/Bl[c][f] ----------------
__global__ void k_wt(const float* __restrict__ W1, unsigned short* __restrict__ Bh,
                     unsigned short* __restrict__ Bl) {
    int i = blockIdx.x * 256 + threadIdx.x;
    if (i >= C1 * F_IN) return;
    int c = i >> 9, f = i & 511;
    float v = W1[(c >> 3) * (F_IN * F_HID) + f * F_HID + (c & 7)];
    unsigned bits = __float_as_uint(v);
    float r = v - __uint_as_float(bits & 0xFFFF0000u);
    Bh[i] = (unsigned short)(bits >> 16);
    Bl[i] = (unsigned short)(__float_as_uint(r) >> 16);
}

// ---------------- GEMM1: X[50000,512] @ W[512,64] -> Wh bf16 ----------------
// 256 thr / 4 waves / 64 rows. B hi/lo in LDS per K-chunk of 128.
// X read once, depth-4 register prefetch (4 dependent HBM rounds per wave total).
__launch_bounds__(256)
__global__ void k_gemm1(const float* __restrict__ X, const unsigned short* __restrict__ Bh,
                        const unsigned short* __restrict__ Bl, unsigned short* __restrict__ Wh) {
    __shared__ unsigned short sBh[64][136];
    __shared__ unsigned short sBl[64][136];
    const int t = threadIdx.x;
    const int lane = t & 63, w = t >> 6;
    const int r0 = blockIdx.x * 64 + w * 16;
    const int m = lane & 15, quad = lane >> 4;
    int row = r0 + m; if (row >= N_NODES) row = N_NODES - 1;
    const float* xrow = X + (size_t)row * F_IN + quad * 8;

    const int sc = t >> 2;        // staging col 0..63
    const int sp = t & 3;         // staging quarter 0..3

    f32x4 acc[4] = {};
    float4 pxa[4], pxb[4];
    #pragma unroll
    for (int i = 0; i < 4; i++) {
        pxa[i] = *(const float4*)(xrow + i * 32);
        pxb[i] = *(const float4*)(xrow + i * 32 + 4);
    }

    for (int chunk = 0; chunk < 4; chunk++) {
        const int k0 = chunk * 128;
        if (chunk) __syncthreads();
        #pragma unroll
        for (int i = 0; i < 4; i++) {
            *(short8*)(&sBh[sc][sp * 32 + i * 8]) =
                *(const short8*)(Bh + sc * F_IN + k0 + sp * 32 + i * 8);
            *(short8*)(&sBl[sc][sp * 32 + i * 8]) =
                *(const short8*)(Bl + sc * F_IN + k0 + sp * 32 + i * 8);
        }
        __syncthreads();
        #pragma unroll
        for (int i = 0; i < 4; i++) {
            float xs[8] = {pxa[i].x, pxa[i].y, pxa[i].z, pxa[i].w,
                           pxb[i].x, pxb[i].y, pxb[i].z, pxb[i].w};
            if (chunk < 3) {                      // prefetch same slot, next chunk
                const int ktn = k0 + 128 + i * 32;
                pxa[i] = *(const float4*)(xrow + ktn);
                pxb[i] = *(const float4*)(xrow + ktn + 4);
            }
            short8 ah, al;
            #pragma unroll
            for (int j = 0; j < 8; j++) {
                unsigned bits = __float_as_uint(xs[j]);
                float r = xs[j] - __uint_as_float(bits & 0xFFFF0000u);
                ah[j] = (short)(bits >> 16);
                al[j] = (short)(__float_as_uint(r) >> 16);
            }
            #pragma unroll
            for (int s = 0; s < 4; s++) {
                short8 bh = *(const short8*)(&sBh[s * 16 + m][i * 32 + quad * 8]);
                short8 bl = *(const short8*)(&sBl[s * 16 + m][i * 32 + quad * 8]);
                acc[s] = __builtin_amdgcn_mfma_f32_16x16x32_bf16(al, bh, acc[s], 0, 0, 0);
                acc[s] = __builtin_amdgcn_mfma_f32_16x16x32_bf16(ah, bl, acc[s], 0, 0, 0);
                acc[s] = __builtin_amdgcn_mfma_f32_16x16x32_bf16(ah, bh, acc[s], 0, 0, 0);
            }
        }
    }
    #pragma unroll
    for (int s = 0; s < 4; s++)
        #pragma unroll
        for (int reg = 0; reg < 4; reg++) {
            int gr = r0 + quad * 4 + reg;
            if (gr < N_NODES)
                Wh[(size_t)gr * 64 + s * 16 + m] = f2bf(acc[s][reg]);
        }
}

// ---------------- pack layer-1 record: [es(8f32)|Wh(64bf16)] + ed array ----------------
__global__ void k_pack1(const unsigned short* __restrict__ Wh, const float* __restrict__ a_s,
                        const float* __restrict__ a_d, char* __restrict__ rec,
                        float* __restrict__ ed) {
    int i = blockIdx.x * 256 + threadIdx.x;
    if (i >= N_NODES * H1) return;
    int n = i >> 3, h = i & 7;
    uint4 u = *(const uint4*)(Wh + (size_t)n * 64 + h * 8);
    float v[8] = {bf_lo(u.x), bf_hi(u.x), bf_lo(u.y), bf_hi(u.y),
                  bf_lo(u.z), bf_hi(u.z), bf_lo(u.w), bf_hi(u.w)};
    float s = 0.f, d = 0.f;
    #pragma unroll
    for (int j = 0; j < 8; j++) {
        s += v[j] * a_s[h * 8 + j];
        d += v[j] * a_d[h * 8 + j];
    }
    char* r = rec + (size_t)n * REC1;
    *(float*)(r + h * 4) = s;
    *(uint4*)(r + 32 + h * 16) = u;
    ed[i] = d;
}

// ---------------- CSR build ----------------
__global__ void k_hist(const int* __restrict__ dst, int* __restrict__ deg) {
    int e4 = (blockIdx.x * 256 + threadIdx.x) * 4;
    if (e4 >= N_EDGES) return;
    int4 d4 = *(const int4*)(dst + e4);
    atomicAdd(&deg[d4.x], 1);
    atomicAdd(&deg[d4.y], 1);
    atomicAdd(&deg[d4.z], 1);
    atomicAdd(&deg[d4.w], 1);
}

__global__ void k_scan1(const int* __restrict__ deg, int* __restrict__ rowptr,
                        int* __restrict__ bsums) {
    __shared__ int s[256];
    int t = threadIdx.x;
    int g = blockIdx.x * 256 + t;
    int v = (g < N_NODES) ? deg[g] : 0;
    s[t] = v;
    __syncthreads();
    #pragma unroll
    for (int off = 1; off < 256; off <<= 1) {
        int a = s[t];
        int b = (t >= off) ? s[t - off] : 0;
        __syncthreads();
        s[t] = a + b;
        __syncthreads();
    }
    if (g < N_NODES) rowptr[g] = s[t] - v;
    if (t == 255) bsums[blockIdx.x] = s[t];
}

// fused scan2+scan3: each block re-scans the 196 block sums, adds its offset
__global__ void k_scan23(const int* __restrict__ bsums, int* __restrict__ rowptr) {
    __shared__ int s[256];
    int t = threadIdx.x;
    s[t] = (t < NBLK_SCAN) ? bsums[t] : 0;
    __syncthreads();
    #pragma unroll
    for (int off = 1; off < 256; off <<= 1) {
        int a = s[t];
        int b = (t >= off) ? s[t - off] : 0;
        __syncthreads();
        s[t] = a + b;
        __syncthreads();
    }
    int boff = (blockIdx.x == 0) ? 0 : s[blockIdx.x - 1];
    int g = blockIdx.x * 256 + t;
    if (g < N_NODES) rowptr[g] += boff;
}

// scatter: post-increment rowptr itself (rowptr[n] ends at start+deg; agg subtracts deg)
__global__ void k_scatter(const int* __restrict__ src, const int* __restrict__ dst,
                          int* __restrict__ rowptr, int* __restrict__ col) {
    int e4 = (blockIdx.x * 256 + threadIdx.x) * 4;
    if (e4 >= N_EDGES) return;
    int4 s4 = *(const int4*)(src + e4);
    int4 d4 = *(const int4*)(dst + e4);
    col[atomicAdd(&rowptr[d4.x], 1)] = s4.x;
    col[atomicAdd(&rowptr[d4.y], 1)] = s4.y;
    col[atomicAdd(&rowptr[d4.z], 1)] = s4.z;
    col[atomicAdd(&rowptr[d4.w], 1)] = s4.w;
}

// ---------------- layer-1 aggregation: record gather, single pass, 2x unroll ----------
__launch_bounds__(256)
__global__ void k_agg1(const char* __restrict__ rec, const float* __restrict__ ed,
                       const int* __restrict__ rowptr, const int* __restrict__ deg,
                       const int* __restrict__ col, float* __restrict__ h2) {
    int wv = threadIdx.x >> 6, lane = threadIdx.x & 63;
    int n = blockIdx.x * 4 + wv;
    if (n >= N_NODES) return;
    int d = deg[n];
    int start = rowptr[n] - d;      // rowptr was post-incremented by scatter
    int g = lane >> 3, q = lane & 7;
    float edq = ed[n * 8 + q];

    float den = 0.f;
    float acc[8] = {};
    for (int base = 0; base < d; base += 16) {
        int e0 = base + g, e1 = base + 8 + g;
        int sv0 = col[start + min(e0, d - 1)];
        int sv1 = col[start + min(e1, d - 1)];
        const char* r0 = rec + (size_t)sv0 * REC1;
        const char* r1 = rec + (size_t)sv1 * REC1;
        float x0 = *(const float*)(r0 + q * 4) + edq;
        float x1 = *(const float*)(r1 + q * 4) + edq;
        uint4 u0 = *(const uint4*)(r0 + 32 + q * 16);
        uint4 u1 = *(const uint4*)(r1 + 32 + q * 16);
        x0 = x0 > 0.f ? x0 : SLOPE * x0;
        x1 = x1 > 0.f ? x1 : SLOPE * x1;
        float w0 = (e0 < d) ? __expf(x0) : 0.f;
        float w1 = (e1 < d) ? __expf(x1) : 0.f;
        den += w0 + w1;
        float f0[8] = {bf_lo(u0.x), bf_hi(u0.x), bf_lo(u0.y), bf_hi(u0.y),
                       bf_lo(u0.z), bf_hi(u0.z), bf_lo(u0.w), bf_hi(u0.w)};
        float f1[8] = {bf_lo(u1.x), bf_hi(u1.x), bf_lo(u1.y), bf_hi(u1.y),
                       bf_lo(u1.z), bf_hi(u1.z), bf_lo(u1.w), bf_hi(u1.w)};
        #pragma unroll
        for (int j = 0; j < 8; j++) acc[j] += w0 * f0[j] + w1 * f1[j];
    }
    #pragma unroll
    for (int off = 8; off <= 32; off <<= 1) {
        den += __shfl_xor(den, off);
        #pragma unroll
        for (int j = 0; j < 8; j++) acc[j] += __shfl_xor(acc[j], off);
    }
    if (g == 0) {
        float inv = 1.f / (den + 1e-10f);
        float o[8];
        #pragma unroll
        for (int j = 0; j < 8; j++) {
            float v = acc[j] * inv;
            o[j] = v > 0.f ? v : expm1f(v);   // fused ELU
        }
        float4* hp = (float4*)(h2 + (size_t)n * 64 + q * 8);
        hp[0] = make_float4(o[0], o[1], o[2], o[3]);
        hp[1] = make_float4(o[4], o[5], o[6], o[7]);
    }
}

// ---------------- GEMM2 (K=64), 16 nodes/block; writes record2 + ed2 ----------------
__launch_bounds__(256)
__global__ void k_gemm2(const float* __restrict__ h2, const float* __restrict__ W2,
                        const float* __restrict__ a2s, const float* __restrict__ a2d,
                        char* __restrict__ rec2, float* __restrict__ ed2) {
    __shared__ float Ws[64 * 64];
    __shared__ float hs[16][64];
    int t = threadIdx.x;
    int n0 = blockIdx.x * 16;
    #pragma unroll
    for (int i = 0; i < 4; i++) {
        int flat = i * 256 + t;
        *(float4*)(Ws + flat * 4) = *(const float4*)(W2 + flat * 4);
    }
    #pragma unroll
    for (int i = 0; i < 4; i++) {
        int flat = i * 256 + t;
        hs[flat >> 6][flat & 63] = h2[(size_t)(n0 + (flat >> 6)) * 64 + (flat & 63)];
    }
    __syncthreads();
    int wv = t >> 6, lane = t & 63;
    float as = a2s[lane], ad = a2d[lane];
    #pragma unroll
    for (int j = 0; j < 4; j++) {
        int nl = wv * 4 + j;
        int n = n0 + nl;
        float acc = 0.f;
        #pragma unroll
        for (int k = 0; k < 64; k++) acc += hs[nl][k] * Ws[k * 64 + lane];
        char* r = rec2 + (size_t)n * REC2;
        *(unsigned short*)(r + 16 + lane * 2) = f2bf(acc);
        float s = acc * as;
        float dd = acc * ad;
        #pragma unroll
        for (int off = 1; off < 64; off <<= 1) {
            s += __shfl_xor(s, off);
            dd += __shfl_xor(dd, off);
        }
        if (lane == 0) { *(float*)r = s; ed2[n] = dd; }
    }
}

// ---------------- layer-2 aggregation (record2) + fused final softmax ----------------
__launch_bounds__(256)
__global__ void k_agg2(const char* __restrict__ rec2, const float* __restrict__ ed2,
                       const int* __restrict__ rowptr, const int* __restrict__ deg,
                       const int* __restrict__ col, float* __restrict__ out) {
    int wv = threadIdx.x >> 6, lane = threadIdx.x & 63;
    int n = blockIdx.x * 4 + wv;
    if (n >= N_NODES) return;
    int d = deg[n];
    int start = rowptr[n] - d;
    int g = lane >> 3, q = lane & 7;
    float edn = ed2[n];

    float den = 0.f;
    float acc[8] = {};
    for (int base = 0; base < d; base += 16) {
        int e0 = base + g, e1 = base + 8 + g;
        int sv0 = col[start + min(e0, d - 1)];
        int sv1 = col[start + min(e1, d - 1)];
        const char* r0 = rec2 + (size_t)sv0 * REC2;
        const char* r1 = rec2 + (size_t)sv1 * REC2;
        float x0 = *(const float*)r0 + edn;
        float x1 = *(const float*)r1 + edn;
        uint4 u0 = *(const uint4*)(r0 + 16 + q * 16);
        uint4 u1 = *(const uint4*)(r1 + 16 + q * 16);
        x0 = x0 > 0.f ? x0 : SLOPE * x0;
        x1 = x1 > 0.f ? x1 : SLOPE * x1;
        float w0 = (e0 < d) ? __expf(x0) : 0.f;
        float w1 = (e1 < d) ? __expf(x1) : 0.f;
        den += w0 + w1;
        float f0[8] = {bf_lo(u0.x), bf_hi(u0.x), bf_lo(u0.y), bf_hi(u0.y),
                       bf_lo(u0.z), bf_hi(u0.z), bf_lo(u0.w), bf_hi(u0.w)};
        float f1[8] = {bf_lo(u1.x), bf_hi(u1.x), bf_lo(u1.y), bf_hi(u1.y),
                       bf_lo(u1.z), bf_hi(u1.z), bf_lo(u1.w), bf_hi(u1.w)};
        #pragma unroll
        for (int j = 0; j < 8; j++) acc[j] += w0 * f0[j] + w1 * f1[j];
    }
    #pragma unroll
    for (int off = 8; off <= 32; off <<= 1) {
        den += __shfl_xor(den, off);
        #pragma unroll
        for (int j = 0; j < 8; j++) acc[j] += __shfl_xor(acc[j], off);
    }
    float inv = 1.f / (den + 1e-10f);
    float o[8];
    #pragma unroll
    for (int j = 0; j < 8; j++) o[j] = acc[j] * inv;
    float mx = o[0];
    #pragma unroll
    for (int j = 1; j < 8; j++) mx = fmaxf(mx, o[j]);
    mx = fmaxf(mx, __shfl_xor(mx, 1));
    mx = fmaxf(mx, __shfl_xor(mx, 2));
    mx = fmaxf(mx, __shfl_xor(mx, 4));
    float e8[8], sm = 0.f;
    #pragma unroll
    for (int j = 0; j < 8; j++) { e8[j] = __expf(o[j] - mx); sm += e8[j]; }
    sm += __shfl_xor(sm, 1);
    sm += __shfl_xor(sm, 2);
    sm += __shfl_xor(sm, 4);
    if (g == 0) {
        float inv2 = 1.f / sm;
        float4* op = (float4*)(out + (size_t)n * 64 + q * 8);
        op[0] = make_float4(e8[0] * inv2, e8[1] * inv2, e8[2] * inv2, e8[3] * inv2);
        op[1] = make_float4(e8[4] * inv2, e8[5] * inv2, e8[6] * inv2, e8[7] * inv2);
    }
}

// ---------------- launcher ----------------
extern "C" void kernel_launch(void* const* d_in, const int* in_sizes, int n_in,
                              void* d_out, int out_size, void* d_ws, size_t ws_size,
                              hipStream_t stream) {
    const float* X   = (const float*)d_in[0];
    const float* W1  = (const float*)d_in[1];
    const float* a1s = (const float*)d_in[2];
    const float* a1d = (const float*)d_in[3];
    const float* W2  = (const float*)d_in[4];
    const float* a2s = (const float*)d_in[5];
    const float* a2d = (const float*)d_in[6];
    const int*   src = (const int*)d_in[7];
    const int*   dst = (const int*)d_in[8];
    float* out = (float*)d_out;

    char* w = (char*)d_ws;
    size_t off = 0;
    auto alloc = [&](size_t bytes) {
        void* p = w + off;
        off += (bytes + 255) & ~(size_t)255;
        return p;
    };
    unsigned short* Bh  = (unsigned short*)alloc((size_t)C1 * F_IN * 2);
    unsigned short* Bl  = (unsigned short*)alloc((size_t)C1 * F_IN * 2);
    unsigned short* WH1 = (unsigned short*)alloc((size_t)N_NODES * 64 * 2);
    char*  rec1  = (char*)alloc((size_t)N_NODES * REC1);
    char*  rec2  = (char*)alloc((size_t)N_NODES * REC2);
    float* h2    = (float*)alloc((size_t)N_NODES * 64 * 4);
    float* ed1   = (float*)alloc((size_t)N_NODES * 8 * 4);
    float* ed2   = (float*)alloc((size_t)N_NODES * 4);
    int*   deg   = (int*)alloc((size_t)N_NODES * 4);
    int*   rowptr= (int*)alloc((size_t)N_NODES * 4);
    int*   col   = (int*)alloc((size_t)N_EDGES * 4);
    int*   bsums = (int*)alloc(256 * 4);

    hipMemsetAsync(deg, 0, (size_t)N_NODES * 4, stream);

    // CSR build
    k_hist<<<(N_EDGES / 4 + 255) / 256, 256, 0, stream>>>(dst, deg);
    k_scan1<<<NBLK_SCAN, 256, 0, stream>>>(deg, rowptr, bsums);
    k_scan23<<<NBLK_SCAN, 256, 0, stream>>>(bsums, rowptr);
    k_scatter<<<(N_EDGES / 4 + 255) / 256, 256, 0, stream>>>(src, dst, rowptr, col);

    // layer 1
    k_wt<<<(C1 * F_IN + 255) / 256, 256, 0, stream>>>(W1, Bh, Bl);
    k_gemm1<<<(N_NODES + 63) / 64, 256, 0, stream>>>(X, Bh, Bl, WH1);
    k_pack1<<<(N_NODES * H1 + 255) / 256, 256, 0, stream>>>(WH1, a1s, a1d, rec1, ed1);
    k_agg1<<<(N_NODES + 3) / 4, 256, 0, stream>>>(rec1, ed1, rowptr, deg, col, h2);

    // layer 2
    k_gemm2<<<N_NODES / 16, 256, 0, stream>>>(h2, W2, a2s, a2d, rec2, ed2);
    k_agg2<<<(N_NODES + 3) / 4, 256, 0, stream>>>(rec2, ed2, rowptr, deg, col, out);
}